// Round 10
// baseline (138.331 us; speedup 1.0000x reference)
//
#include <hip/hip_runtime.h>
#include <math.h>

// Problem constants
#define BB    16
#define TT    2048
#define VOCAB 14
#define TOKD  8
#define POSD  8
#define DM    16      // TOKD + POSD
#define NH    2
#define HD    3
#define AD    6       // NH*HD
#define FFND  3

#define NTOK  (BB*TT)            // 32768
#define BH    (BB*NH)            // 32
// 128-key chunks: per bh, s=0..7 (256-query rows) x chunks c=0..2s+1 -> 72
// tiles/bh, 2304 blocks (~8/CU steady state = 8 waves/SIMD, 1.8x the TLP of
// the 256-key version). Ordering: 2048 "main" tiles (c<=2s) first, the 256
// light half-diagonal tiles (c=2s+1, ~25% work) last to absorb the tail.
#define NMAIN 2048
#define NTILE3 2304

struct P {
    const int*   idx;
    const float* tok_emb;
    const float* pos_enc;
    const float* Wq;
    const float* Wk;
    const float* Wv;
    const float* Wo;
    const float* ln1w;
    const float* ln1b;
    const float* ln2w;
    const float* ln2b;
    const float* lnfw;
    const float* lnfb;
    const float* W1;
    const float* b1;
    const float* W2;
    const float* b2;
    const float* Wh;
    float*       out;
    float4*      pbuf;   // [BH][16][TT] chunk partials {a0,a1,a2,l}, transposed
};

// LN1 output for token (b, t): embeddings gather + layernorm.
__device__ __forceinline__ void ln1_of(const P& p, int b, int t, float* h) {
    float x[DM];
    int tok = p.idx[b * TT + t];
    #pragma unroll
    for (int j = 0; j < TOKD; ++j) x[j]        = p.tok_emb[tok * TOKD + j];
    #pragma unroll
    for (int j = 0; j < POSD; ++j) x[TOKD + j] = p.pos_enc[t * POSD + j];

    float m = 0.f;
    #pragma unroll
    for (int j = 0; j < DM; ++j) m += x[j];
    m *= (1.f / DM);
    float v = 0.f;
    #pragma unroll
    for (int j = 0; j < DM; ++j) { float d = x[j] - m; v += d * d; }
    v *= (1.f / DM);
    float rs = rsqrtf(v + 1e-5f);
    #pragma unroll
    for (int j = 0; j < DM; ++j)
        h[j] = (x[j] - m) * rs * p.ln1w[j] + p.ln1b[j];
}

#define LOADKV(it)                                                             \
    float4 Kr = skv[((kw + (it)) << 1)];                                       \
    float4 Vr = skv[((kw + (it)) << 1) + 1];                                   \
    float k0 = Kr.x, k1 = Kr.y, k2 = Kr.z;                                     \
    float v0 = Vr.x, v1 = Vr.y, v2 = Vr.z;

// ---------------------------------------------------------------------------
// Kernel 1: attention tiles, 128-key chunks for 8 waves/SIMD occupancy.
// Tile = (bh, 256-query row s, 128-key chunk c), c <= 2s+1. Wave wv owns
// keys [c*128+32wv, +32); lane owns queries 64j+lane, j=0..3. One broadcast
// ds_read_b128 pair per key serves 256 query*key pairs (same as the proven
// structure). LDS is a 16 KB union: {skv 4K, sq 4K} before the post-loop
// barrier, spart 16K after -> 8 blocks/CU capacity. Diagonal chunks
// (ko = 128c-256s in {0,128}): per-(wave,group) wave-uniform classification
// skip / unmasked / per-pair-masked.
// ---------------------------------------------------------------------------
__global__ __launch_bounds__(256, 8) void attn_kernel(P p) {
    __shared__ float4 smem[1024];    // 16 KB union
    float4* skv = smem;              // [0,256)   128 keys x {K,V}
    float4* sq  = smem + 256;        // [256,512) 256 prescaled q
    float4* spart = smem;            // full arena after barrier 2

    const int tid = threadIdx.x;
    int bid = blockIdx.x;
    int bh, s, c;
    if (bid < NMAIN) {               // main tiles: c in 0..2s (count (s+1)^2-s^2... prefix s^2)
        bh = bid >> 6;
        int rr = bid & 63;
        s = 0;
        while ((s + 1) * (s + 1) <= rr) ++s;
        c = rr - s * s;
    } else {                         // half-diagonal tiles: c = 2s+1
        int k = bid - NMAIN;
        bh = k >> 3;
        s  = k & 7;
        c  = 2 * s + 1;
    }
    int b  = bh >> 1;                // NH = 2
    int hh = bh & 1;
    int ko = (c << 7) - (s << 8);    // key offset rel. query base; <0 => unmasked

    // --- inline prep: queries (all threads), keys (tid<128), this head only
    {
        float hQ[DM];
        ln1_of(p, b, (s << 8) + tid, hQ);
        const float QS = 1.4426950408889634f / 1.7320508075688772f; // log2e/sqrt(HD)
        float q0=0.f,q1=0.f,q2=0.f;
        const float* wq = p.Wq + (hh * 3) * 8;
        #pragma unroll
        for (int j = 0; j < 8; ++j) {
            q0 = fmaf(wq[j],      hQ[TOKD + j], q0);
            q1 = fmaf(wq[8 + j],  hQ[TOKD + j], q1);
            q2 = fmaf(wq[16 + j], hQ[TOKD + j], q2);
        }
        sq[tid] = make_float4(q0 * QS, q1 * QS, q2 * QS, 0.f);

        if (tid < 128) {
            float hK[DM];
            if (ko == 0) {           // c == 2s: key token == own query token
                #pragma unroll
                for (int j = 0; j < DM; ++j) hK[j] = hQ[j];
            } else {
                ln1_of(p, b, (c << 7) + tid, hK);
            }
            float k0=0.f,k1=0.f,k2=0.f,v0=0.f,v1=0.f,v2=0.f;
            const float* wk  = p.Wk + (hh * 3) * 8;
            const float* wv_ = p.Wv + (hh * 3) * 8;
            #pragma unroll
            for (int j = 0; j < 8; ++j) {
                k0 = fmaf(wk[j],      hK[TOKD + j], k0);
                k1 = fmaf(wk[8 + j],  hK[TOKD + j], k1);
                k2 = fmaf(wk[16 + j], hK[TOKD + j], k2);
                v0 = fmaf(wv_[j],      hK[j], v0);
                v1 = fmaf(wv_[8 + j],  hK[j], v1);
                v2 = fmaf(wv_[16 + j], hK[j], v2);
            }
            skv[(tid << 1)]     = make_float4(k0, k1, k2, 0.f);
            skv[(tid << 1) + 1] = make_float4(v0, v1, v2, 0.f);
        }
    }
    __syncthreads();

    int wv   = tid >> 6;
    int lane = tid & 63;
    int kw   = wv << 5;              // local key base (32 keys per wave)

    float4 qr[4];
    #pragma unroll
    for (int j = 0; j < 4; ++j) qr[j] = sq[(j << 6) + lane];

    float ac[4][4];
    #pragma unroll
    for (int j = 0; j < 4; ++j)
        ac[j][0] = ac[j][1] = ac[j][2] = ac[j][3] = 0.f;

    if (ko < 0) {
        // fully unmasked: one K/V read serves all 4 query groups
        #pragma unroll 8
        for (int it = 0; it < 32; ++it) {
            LOADKV(it)
            #pragma unroll
            for (int j = 0; j < 4; ++j) {
                float sc = fmaf(qr[j].x, k0, fmaf(qr[j].y, k1, qr[j].z * k2));
                float pr = __builtin_amdgcn_exp2f(sc);
                ac[j][0] = fmaf(pr, v0, ac[j][0]);
                ac[j][1] = fmaf(pr, v1, ac[j][1]);
                ac[j][2] = fmaf(pr, v2, ac[j][2]);
                ac[j][3] += pr;
            }
        }
    } else {
        // diagonal chunk: keys klo..klo+31 (rel. query base) vs queries
        // 64j..64j+63. Wave-uniform per-group classification.
        int klo = ko + kw;
        #pragma unroll
        for (int j = 0; j < 4; ++j) {
            int qlo = j << 6;
            if (klo > qlo + 63) continue;          // fully masked
            if (klo + 31 <= qlo) {                 // fully unmasked
                #pragma unroll 8
                for (int it = 0; it < 32; ++it) {
                    LOADKV(it)
                    float sc = fmaf(qr[j].x, k0, fmaf(qr[j].y, k1, qr[j].z * k2));
                    float pr = __builtin_amdgcn_exp2f(sc);
                    ac[j][0] = fmaf(pr, v0, ac[j][0]);
                    ac[j][1] = fmaf(pr, v1, ac[j][1]);
                    ac[j][2] = fmaf(pr, v2, ac[j][2]);
                    ac[j][3] += pr;
                }
            } else {                               // triangular crossing
                #pragma unroll 8
                for (int it = 0; it < 32; ++it) {
                    LOADKV(it)
                    float sc = fmaf(qr[j].x, k0, fmaf(qr[j].y, k1, qr[j].z * k2));
                    float pr = __builtin_amdgcn_exp2f(sc);
                    pr = (klo + it <= qlo + lane) ? pr : 0.f;
                    ac[j][0] = fmaf(pr, v0, ac[j][0]);
                    ac[j][1] = fmaf(pr, v1, ac[j][1]);
                    ac[j][2] = fmaf(pr, v2, ac[j][2]);
                    ac[j][3] += pr;
                }
            }
        }
    }

    __syncthreads();                 // union safety: all skv/sq reads done

    // per-wave partials (16B lane stride: 2-way, free)
    #pragma unroll
    for (int j = 0; j < 4; ++j)
        spart[(wv << 8) + (j << 6) + lane] =
            make_float4(ac[j][0], ac[j][1], ac[j][2], ac[j][3]);
    __syncthreads();

    // block reduce across 4 waves; coalesced transposed pbuf store
    float4 p0 = spart[tid];
    float4 p1 = spart[256 + tid];
    float4 p2 = spart[512 + tid];
    float4 p3 = spart[768 + tid];
    float4 acc = make_float4(p0.x+p1.x+p2.x+p3.x, p0.y+p1.y+p2.y+p3.y,
                             p0.z+p1.z+p2.z+p3.z, p0.w+p1.w+p2.w+p3.w);
    p.pbuf[((size_t)(bh << 4) + c) * TT + (s << 8) + tid] = acc;
}

// ---------------------------------------------------------------------------
// Kernel 2: per-token epilogue (proven version; 16 chunks of 128 keys).
// ---------------------------------------------------------------------------
__global__ __launch_bounds__(256) void epi_kernel(P p) {
    int gid = blockIdx.x * 256 + threadIdx.x;
    if (gid >= NTOK) return;
    int t = gid & (TT - 1);
    int b = gid >> 11;
    int s16 = t >> 7;                // last valid 128-key chunk

    float x[DM];
    int tok = p.idx[gid];
    #pragma unroll
    for (int j = 0; j < TOKD; ++j) x[j]        = p.tok_emb[tok * TOKD + j];
    #pragma unroll
    for (int j = 0; j < POSD; ++j) x[TOKD + j] = p.pos_enc[t * POSD + j];

    float att[AD];
    #pragma unroll
    for (int hh = 0; hh < NH; ++hh) {
        const float4* pp = p.pbuf + ((size_t)((b * NH + hh) << 4)) * TT + t;
        float4 acc = pp[0];
        for (int c = 1; c <= s16; ++c) {
            float4 e = pp[(size_t)c * TT];
            acc.x += e.x; acc.y += e.y; acc.z += e.z; acc.w += e.w;
        }
        float inv = 1.f / acc.w;
        att[hh*3+0] = acc.x * inv;
        att[hh*3+1] = acc.y * inv;
        att[hh*3+2] = acc.z * inv;
    }

    float xo[DM];
    #pragma unroll
    for (int j = 0; j < DM; ++j) {
        float sacc = x[j];
        #pragma unroll
        for (int a = 0; a < AD; ++a) sacc = fmaf(p.Wo[j * AD + a], att[a], sacc);
        xo[j] = sacc;
    }

    float m = 0.f;
    #pragma unroll
    for (int j = 0; j < DM; ++j) m += xo[j];
    m *= (1.f / DM);
    float v = 0.f;
    #pragma unroll
    for (int j = 0; j < DM; ++j) { float d = xo[j] - m; v += d * d; }
    v *= (1.f / DM);
    float rs = rsqrtf(v + 1e-5f);
    float h2[DM];
    #pragma unroll
    for (int j = 0; j < DM; ++j)
        h2[j] = (xo[j] - m) * rs * p.ln2w[j] + p.ln2b[j];

    float g[FFND];
    #pragma unroll
    for (int cc = 0; cc < FFND; ++cc) {
        float f = p.b1[cc];
        #pragma unroll
        for (int j = 0; j < DM; ++j) f = fmaf(p.W1[cc * DM + j], h2[j], f);
        g[cc] = 0.5f * f * (1.f + erff(f * 0.70710678118654752f));
    }
    float x2[DM];
    #pragma unroll
    for (int j = 0; j < DM; ++j) {
        float sacc = xo[j] + p.b2[j];
        #pragma unroll
        for (int cc = 0; cc < FFND; ++cc) sacc = fmaf(p.W2[j * FFND + cc], g[cc], sacc);
        x2[j] = sacc;
    }

    m = 0.f;
    #pragma unroll
    for (int j = 0; j < DM; ++j) m += x2[j];
    m *= (1.f / DM);
    v = 0.f;
    #pragma unroll
    for (int j = 0; j < DM; ++j) { float d = x2[j] - m; v += d * d; }
    v *= (1.f / DM);
    rs = rsqrtf(v + 1e-5f);
    float y[DM];
    #pragma unroll
    for (int j = 0; j < DM; ++j)
        y[j] = (x2[j] - m) * rs * p.lnfw[j] + p.lnfb[j];

    float t8[TOKD];
    #pragma unroll
    for (int pp = 0; pp < TOKD; ++pp) {
        float sacc = 0.f;
        #pragma unroll
        for (int j = 0; j < DM; ++j) sacc = fmaf(p.Wh[pp * DM + j], y[j], sacc);
        t8[pp] = sacc;
    }
    float* op = p.out + (size_t)gid * VOCAB;
    #pragma unroll
    for (int vcb = 0; vcb < VOCAB; ++vcb) {
        float sacc = 0.f;
        #pragma unroll
        for (int pp = 0; pp < TOKD; ++pp)
            sacc = fmaf(t8[pp], p.tok_emb[vcb * TOKD + pp], sacc);
        op[vcb] = sacc;
    }
}

// ---------------------------------------------------------------------------
extern "C" void kernel_launch(void* const* d_in, const int* in_sizes, int n_in,
                              void* d_out, int out_size, void* d_ws, size_t ws_size,
                              hipStream_t stream) {
    P p;
    p.idx     = (const int*)d_in[0];
    p.tok_emb = (const float*)d_in[1];
    p.pos_enc = (const float*)d_in[2];
    p.Wq      = (const float*)d_in[3];
    p.Wk      = (const float*)d_in[4];
    p.Wv      = (const float*)d_in[5];
    p.Wo      = (const float*)d_in[6];
    p.ln1w    = (const float*)d_in[7];
    p.ln1b    = (const float*)d_in[8];
    p.ln2w    = (const float*)d_in[9];
    p.ln2b    = (const float*)d_in[10];
    p.lnfw    = (const float*)d_in[11];
    p.lnfb    = (const float*)d_in[12];
    p.W1      = (const float*)d_in[13];
    p.b1      = (const float*)d_in[14];
    p.W2      = (const float*)d_in[15];
    p.b2      = (const float*)d_in[16];
    p.Wh      = (const float*)d_in[17];
    p.out     = (float*)d_out;
    p.pbuf    = (float4*)d_ws;                                  // 16 MB

    attn_kernel<<<NTILE3, 256, 0, stream>>>(p);
    epi_kernel<<<NTOK / 256, 256, 0, stream>>>(p);
}

// Round 11
// 121.673 us; speedup vs baseline: 1.1369x; 1.1369x over previous
//
#include <hip/hip_runtime.h>
#include <math.h>

// Problem constants
#define BB    16
#define TT    2048
#define VOCAB 14
#define TOKD  8
#define POSD  8
#define DM    16      // TOKD + POSD
#define NH    2
#define HD    3
#define AD    6       // NH*HD
#define FFND  3

#define NTOK  (BB*TT)            // 32768
#define BH    (BB*NH)            // 32
#define TPB   36                 // tiles per bh: sum_{s=0..7}(s+1)
#define NTILE (BH*TPB)           // 1152 equal-cost tiles

typedef float f2 __attribute__((ext_vector_type(2)));
__device__ __forceinline__ f2 fma2(f2 a, f2 b, f2 c) {
    return __builtin_elementwise_fma(a, b, c);   // -> v_pk_fma_f32
}

struct P {
    const int*   idx;
    const float* tok_emb;
    const float* pos_enc;
    const float* Wq;
    const float* Wk;
    const float* Wv;
    const float* Wo;
    const float* ln1w;
    const float* ln1b;
    const float* ln2w;
    const float* ln2b;
    const float* lnfw;
    const float* lnfb;
    const float* W1;
    const float* b1;
    const float* W2;
    const float* b2;
    const float* Wh;
    float*       out;
    float4*      pbuf;   // [BH][8][TT] chunk partials {a0,a1,a2,l}, transposed
};

// LN1 output for token (b, t): embeddings gather + layernorm.
__device__ __forceinline__ void ln1_of(const P& p, int b, int t, float* h) {
    float x[DM];
    int tok = p.idx[b * TT + t];
    #pragma unroll
    for (int j = 0; j < TOKD; ++j) x[j]        = p.tok_emb[tok * TOKD + j];
    #pragma unroll
    for (int j = 0; j < POSD; ++j) x[TOKD + j] = p.pos_enc[t * POSD + j];

    float m = 0.f;
    #pragma unroll
    for (int j = 0; j < DM; ++j) m += x[j];
    m *= (1.f / DM);
    float v = 0.f;
    #pragma unroll
    for (int j = 0; j < DM; ++j) { float d = x[j] - m; v += d * d; }
    v *= (1.f / DM);
    float rs = rsqrtf(v + 1e-5f);
    #pragma unroll
    for (int j = 0; j < DM; ++j)
        h[j] = (x[j] - m) * rs * p.ln1w[j] + p.ln1b[j];
}

// Pair-interleaved K/V LDS layout (3 sections x 128 float4):
//   A[i] = {k0(2i),k0(2i+1),k1(2i),k1(2i+1)}
//   B[i] = {k2(2i),k2(2i+1),v0(2i),v0(2i+1)}
//   C[i] = {v1(2i),v1(2i+1),v2(2i),v2(2i+1)}
#define PAIR_LOAD(i)                                                           \
    float4 A  = skv[aw + (i)];                                                 \
    float4 Bv = skv[128 + aw + (i)];                                           \
    float4 Cv = skv[256 + aw + (i)];                                           \
    f2 k0p = {A.x, A.y},  k1p = {A.z, A.w};                                    \
    f2 k2p = {Bv.x, Bv.y}, v0p = {Bv.z, Bv.w};                                 \
    f2 v1p = {Cv.x, Cv.y}, v2p = {Cv.z, Cv.w};

#define PAIR_STEP(j)                                                           \
    { f2 sc = fma2(qx2[j], k0p, fma2(qy2[j], k1p, qz2[j] * k2p));              \
      f2 pr = {__builtin_amdgcn_exp2f(sc.x), __builtin_amdgcn_exp2f(sc.y)};    \
      a0[j] = fma2(pr, v0p, a0[j]);                                            \
      a1[j] = fma2(pr, v1p, a1[j]);                                            \
      a2[j] = fma2(pr, v2p, a2[j]);                                            \
      al[j] += pr; }

#define PAIR_STEP_TRI(j, i)                                                    \
    { f2 sc = fma2(qx2[j], k0p, fma2(qy2[j], k1p, qz2[j] * k2p));              \
      float pe0 = ((2*(i))   <= lane) ? __builtin_amdgcn_exp2f(sc.x) : 0.f;    \
      float pe1 = ((2*(i)+1) <= lane) ? __builtin_amdgcn_exp2f(sc.y) : 0.f;    \
      f2 pr = {pe0, pe1};                                                      \
      a0[j] = fma2(pr, v0p, a0[j]);                                            \
      a1[j] = fma2(pr, v1p, a1[j]);                                            \
      a2[j] = fma2(pr, v2p, a2[j]);                                            \
      al[j] += pr; }

// ---------------------------------------------------------------------------
// Kernel 1: attention tiles — the proven R9 structure (1152 tiles, inline
// prep, launch_bounds(256,5)) with a PACKED dual-FP32 inner loop: keys
// processed 2 at a time via float2 ext-vectors (compiler-generated
// v_pk_fma_f32 — no inline asm). Per 2 keys per wave: 3 ds_read_b128 +
// ~35 issue slots, vs ~68 scalar — attacks the measured issue-bound regime.
// ---------------------------------------------------------------------------
__global__ __launch_bounds__(256, 5) void attn_kernel(P p) {
    __shared__ float4 skv[384];      // 6 KB  pair-interleaved K/V
    __shared__ float4 sq[256];       // 4 KB  prescaled q
    __shared__ float4 spart[1024];   // 16 KB

    const int tid  = threadIdx.x;
    int tile = blockIdx.x;
    int bh   = tile / TPB;
    int r    = tile - bh * TPB;
    int s    = 0;
    while (((s + 1) * (s + 2)) / 2 <= r) ++s;
    int c    = r - (s * (s + 1)) / 2;
    int b    = bh >> 1;              // NH = 2
    int hh   = bh & 1;

    // --- inline prep: key-token K/V (pair-interleaved), query-token Q
    {
        float hK[DM];
        ln1_of(p, b, (c << 8) + tid, hK);
        float k0=0.f,k1=0.f,k2=0.f,v0=0.f,v1=0.f,v2=0.f;
        const float* wk  = p.Wk + (hh * 3) * 8;
        const float* wv_ = p.Wv + (hh * 3) * 8;
        #pragma unroll
        for (int j = 0; j < 8; ++j) {
            k0 = fmaf(wk[j],      hK[TOKD + j], k0);
            k1 = fmaf(wk[8 + j],  hK[TOKD + j], k1);
            k2 = fmaf(wk[16 + j], hK[TOKD + j], k2);
            v0 = fmaf(wv_[j],      hK[j], v0);
            v1 = fmaf(wv_[8 + j],  hK[j], v1);
            v2 = fmaf(wv_[16 + j], hK[j], v2);
        }
        float* sf = reinterpret_cast<float*>(skv);
        int o4 = ((tid >> 1) << 2) + (tid & 1);
        sf[o4]            = k0;  sf[o4 + 2]        = k1;
        sf[512 + o4]      = k2;  sf[512 + o4 + 2]  = v0;
        sf[1024 + o4]     = v1;  sf[1024 + o4 + 2] = v2;

        float hQ[DM];
        if (c != s) {
            ln1_of(p, b, (s << 8) + tid, hQ);
        } else {
            #pragma unroll
            for (int j = 0; j < DM; ++j) hQ[j] = hK[j];   // same tokens
        }
        const float QS = 1.4426950408889634f / 1.7320508075688772f; // log2e/sqrt(HD)
        float q0=0.f,q1=0.f,q2=0.f;
        const float* wq = p.Wq + (hh * 3) * 8;
        #pragma unroll
        for (int j = 0; j < 8; ++j) {
            q0 = fmaf(wq[j],      hQ[TOKD + j], q0);
            q1 = fmaf(wq[8 + j],  hQ[TOKD + j], q1);
            q2 = fmaf(wq[16 + j], hQ[TOKD + j], q2);
        }
        sq[tid] = make_float4(q0 * QS, q1 * QS, q2 * QS, 0.f);
    }
    __syncthreads();

    int wv   = tid >> 6;
    int lane = tid & 63;
    int aw   = wv << 5;              // pair-entry base (32 pairs = 64 keys)

    f2 qx2[4], qy2[4], qz2[4];
    #pragma unroll
    for (int j = 0; j < 4; ++j) {
        float4 q4 = sq[(j << 6) + lane];
        qx2[j] = (f2){q4.x, q4.x};
        qy2[j] = (f2){q4.y, q4.y};
        qz2[j] = (f2){q4.z, q4.z};
    }

    f2 a0[4], a1[4], a2[4], al[4];
    #pragma unroll
    for (int j = 0; j < 4; ++j) {
        a0[j] = (f2){0.f, 0.f}; a1[j] = (f2){0.f, 0.f};
        a2[j] = (f2){0.f, 0.f}; al[j] = (f2){0.f, 0.f};
    }

    if (c < s) {
        // fully unmasked: one A/B/C read set serves all 4 query groups
        #pragma unroll 4
        for (int i = 0; i < 32; ++i) {
            PAIR_LOAD(i)
            #pragma unroll
            for (int j = 0; j < 4; ++j) PAIR_STEP(j)
        }
    } else {
        // diagonal tile: wave wv sees keys 64wv..64wv+63.
        // group j<wv fully masked (skip); j==wv triangular; j>wv unmasked.
        #pragma unroll
        for (int j = 0; j < 4; ++j) {
            if (j < wv) continue;              // wave-uniform skip
            if (j == wv) {
                #pragma unroll 4
                for (int i = 0; i < 32; ++i) {
                    PAIR_LOAD(i)
                    PAIR_STEP_TRI(j, i)
                }
            } else {
                #pragma unroll 4
                for (int i = 0; i < 32; ++i) {
                    PAIR_LOAD(i)
                    PAIR_STEP(j)
                }
            }
        }
    }

    // merge even/odd halves; per-wave partials (16B lane stride: 2-way, free)
    #pragma unroll
    for (int j = 0; j < 4; ++j)
        spart[(wv << 8) + (j << 6) + lane] =
            make_float4(a0[j].x + a0[j].y, a1[j].x + a1[j].y,
                        a2[j].x + a2[j].y, al[j].x + al[j].y);
    __syncthreads();

    // block reduce across 4 waves; coalesced transposed pbuf store
    float4 p0 = spart[tid];
    float4 p1 = spart[256 + tid];
    float4 p2 = spart[512 + tid];
    float4 p3 = spart[768 + tid];
    float4 acc = make_float4(p0.x+p1.x+p2.x+p3.x, p0.y+p1.y+p2.y+p3.y,
                             p0.z+p1.z+p2.z+p3.z, p0.w+p1.w+p2.w+p3.w);
    p.pbuf[((size_t)bh * 8 + c) * TT + (s << 8) + tid] = acc;
}

// ---------------------------------------------------------------------------
// Kernel 2: per-token epilogue (identical to the proven version).
// ---------------------------------------------------------------------------
__global__ __launch_bounds__(256) void epi_kernel(P p) {
    int gid = blockIdx.x * 256 + threadIdx.x;
    if (gid >= NTOK) return;
    int t = gid & (TT - 1);
    int b = gid >> 11;
    int s = t >> 8;

    float x[DM];
    int tok = p.idx[gid];
    #pragma unroll
    for (int j = 0; j < TOKD; ++j) x[j]        = p.tok_emb[tok * TOKD + j];
    #pragma unroll
    for (int j = 0; j < POSD; ++j) x[TOKD + j] = p.pos_enc[t * POSD + j];

    float att[AD];
    #pragma unroll
    for (int hh = 0; hh < NH; ++hh) {
        const float4* pp = p.pbuf + ((size_t)(b * NH + hh) * 8) * TT + t;
        float4 acc = pp[0];
        for (int c = 1; c <= s; ++c) {
            float4 e = pp[(size_t)c * TT];
            acc.x += e.x; acc.y += e.y; acc.z += e.z; acc.w += e.w;
        }
        float inv = 1.f / acc.w;
        att[hh*3+0] = acc.x * inv;
        att[hh*3+1] = acc.y * inv;
        att[hh*3+2] = acc.z * inv;
    }

    float xo[DM];
    #pragma unroll
    for (int j = 0; j < DM; ++j) {
        float sacc = x[j];
        #pragma unroll
        for (int a = 0; a < AD; ++a) sacc = fmaf(p.Wo[j * AD + a], att[a], sacc);
        xo[j] = sacc;
    }

    float m = 0.f;
    #pragma unroll
    for (int j = 0; j < DM; ++j) m += xo[j];
    m *= (1.f / DM);
    float v = 0.f;
    #pragma unroll
    for (int j = 0; j < DM; ++j) { float d = xo[j] - m; v += d * d; }
    v *= (1.f / DM);
    float rs = rsqrtf(v + 1e-5f);
    float h2[DM];
    #pragma unroll
    for (int j = 0; j < DM; ++j)
        h2[j] = (xo[j] - m) * rs * p.ln2w[j] + p.ln2b[j];

    float g[FFND];
    #pragma unroll
    for (int cc = 0; cc < FFND; ++cc) {
        float f = p.b1[cc];
        #pragma unroll
        for (int j = 0; j < DM; ++j) f = fmaf(p.W1[cc * DM + j], h2[j], f);
        g[cc] = 0.5f * f * (1.f + erff(f * 0.70710678118654752f));
    }
    float x2[DM];
    #pragma unroll
    for (int j = 0; j < DM; ++j) {
        float sacc = xo[j] + p.b2[j];
        #pragma unroll
        for (int cc = 0; cc < FFND; ++cc) sacc = fmaf(p.W2[j * FFND + cc], g[cc], sacc);
        x2[j] = sacc;
    }

    m = 0.f;
    #pragma unroll
    for (int j = 0; j < DM; ++j) m += x2[j];
    m *= (1.f / DM);
    v = 0.f;
    #pragma unroll
    for (int j = 0; j < DM; ++j) { float d = x2[j] - m; v += d * d; }
    v *= (1.f / DM);
    rs = rsqrtf(v + 1e-5f);
    float y[DM];
    #pragma unroll
    for (int j = 0; j < DM; ++j)
        y[j] = (x2[j] - m) * rs * p.lnfw[j] + p.lnfb[j];

    float t8[TOKD];
    #pragma unroll
    for (int pp = 0; pp < TOKD; ++pp) {
        float sacc = 0.f;
        #pragma unroll
        for (int j = 0; j < DM; ++j) sacc = fmaf(p.Wh[pp * DM + j], y[j], sacc);
        t8[pp] = sacc;
    }
    float* op = p.out + (size_t)gid * VOCAB;
    #pragma unroll
    for (int vcb = 0; vcb < VOCAB; ++vcb) {
        float sacc = 0.f;
        #pragma unroll
        for (int pp = 0; pp < TOKD; ++pp)
            sacc = fmaf(t8[pp], p.tok_emb[vcb * TOKD + pp], sacc);
        op[vcb] = sacc;
    }
}

// ---------------------------------------------------------------------------
extern "C" void kernel_launch(void* const* d_in, const int* in_sizes, int n_in,
                              void* d_out, int out_size, void* d_ws, size_t ws_size,
                              hipStream_t stream) {
    P p;
    p.idx     = (const int*)d_in[0];
    p.tok_emb = (const float*)d_in[1];
    p.pos_enc = (const float*)d_in[2];
    p.Wq      = (const float*)d_in[3];
    p.Wk      = (const float*)d_in[4];
    p.Wv      = (const float*)d_in[5];
    p.Wo      = (const float*)d_in[6];
    p.ln1w    = (const float*)d_in[7];
    p.ln1b    = (const float*)d_in[8];
    p.ln2w    = (const float*)d_in[9];
    p.ln2b    = (const float*)d_in[10];
    p.lnfw    = (const float*)d_in[11];
    p.lnfb    = (const float*)d_in[12];
    p.W1      = (const float*)d_in[13];
    p.b1      = (const float*)d_in[14];
    p.W2      = (const float*)d_in[15];
    p.b2      = (const float*)d_in[16];
    p.Wh      = (const float*)d_in[17];
    p.out     = (float*)d_out;
    p.pbuf    = (float4*)d_ws;                                  // 8 MB

    attn_kernel<<<NTILE, 256, 0, stream>>>(p);
    epi_kernel<<<NTOK / 256, 256, 0, stream>>>(p);
}

// Round 12
// 119.416 us; speedup vs baseline: 1.1584x; 1.0189x over previous
//
#include <hip/hip_runtime.h>
#include <math.h>

// Problem constants
#define BB    16
#define TT    2048
#define VOCAB 14
#define TOKD  8
#define POSD  8
#define DM    16      // TOKD + POSD
#define NH    2
#define HD    3
#define AD    6       // NH*HD
#define FFND  3

#define NTOK  (BB*TT)            // 32768
#define BH    (BB*NH)            // 32
#define TPB   36                 // tiles per bh: sum_{s=0..7}(s+1)
#define NTILE (BH*TPB)           // 1152 equal-cost tiles

typedef float f2 __attribute__((ext_vector_type(2)));
__device__ __forceinline__ f2 fma2(f2 a, f2 b, f2 c) {
    return __builtin_elementwise_fma(a, b, c);   // -> v_pk_fma_f32
}

struct P {
    const int*   idx;
    const float* tok_emb;
    const float* pos_enc;
    const float* Wq;
    const float* Wk;
    const float* Wv;
    const float* Wo;
    const float* ln1w;
    const float* ln1b;
    const float* ln2w;
    const float* ln2b;
    const float* lnfw;
    const float* lnfb;
    const float* W1;
    const float* b1;
    const float* W2;
    const float* b2;
    const float* Wh;
    float*       out;
    float4*      pbuf;   // [BH][8][TT] chunk partials {a0,a1,a2,l}, transposed
};

// LN1 output for token (b, t): embeddings gather + layernorm.
__device__ __forceinline__ void ln1_of(const P& p, int b, int t, float* h) {
    float x[DM];
    int tok = p.idx[b * TT + t];
    #pragma unroll
    for (int j = 0; j < TOKD; ++j) x[j]        = p.tok_emb[tok * TOKD + j];
    #pragma unroll
    for (int j = 0; j < POSD; ++j) x[TOKD + j] = p.pos_enc[t * POSD + j];

    float m = 0.f;
    #pragma unroll
    for (int j = 0; j < DM; ++j) m += x[j];
    m *= (1.f / DM);
    float v = 0.f;
    #pragma unroll
    for (int j = 0; j < DM; ++j) { float d = x[j] - m; v += d * d; }
    v *= (1.f / DM);
    float rs = rsqrtf(v + 1e-5f);
    #pragma unroll
    for (int j = 0; j < DM; ++j)
        h[j] = (x[j] - m) * rs * p.ln1w[j] + p.ln1b[j];
}

// Pair-interleaved K/V LDS layout (3 sections x 128 float4):
//   A[i] = {k0(2i),k0(2i+1),k1(2i),k1(2i+1)}
//   B[i] = {k2(2i),k2(2i+1),v0(2i),v0(2i+1)}
//   C[i] = {v1(2i),v1(2i+1),v2(2i),v2(2i+1)}
#define PAIR_LOAD(i)                                                           \
    float4 A  = skv[aw + (i)];                                                 \
    float4 Bv = skv[128 + aw + (i)];                                           \
    float4 Cv = skv[256 + aw + (i)];                                           \
    f2 k0p = {A.x, A.y},  k1p = {A.z, A.w};                                    \
    f2 k2p = {Bv.x, Bv.y}, v0p = {Bv.z, Bv.w};                                 \
    f2 v1p = {Cv.x, Cv.y}, v2p = {Cv.z, Cv.w};

#define PAIR_STEP(j)                                                           \
    { f2 sc = fma2(qx2[j], k0p, fma2(qy2[j], k1p, qz2[j] * k2p));              \
      f2 pr = {__builtin_amdgcn_exp2f(sc.x), __builtin_amdgcn_exp2f(sc.y)};    \
      a0[j] = fma2(pr, v0p, a0[j]);                                            \
      a1[j] = fma2(pr, v1p, a1[j]);                                            \
      a2[j] = fma2(pr, v2p, a2[j]);                                            \
      al[j] += pr; }

#define PAIR_STEP_TRI(j, i)                                                    \
    { f2 sc = fma2(qx2[j], k0p, fma2(qy2[j], k1p, qz2[j] * k2p));              \
      float pe0 = ((2*(i))   <= lane) ? __builtin_amdgcn_exp2f(sc.x) : 0.f;    \
      float pe1 = ((2*(i)+1) <= lane) ? __builtin_amdgcn_exp2f(sc.y) : 0.f;    \
      f2 pr = {pe0, pe1};                                                      \
      a0[j] = fma2(pr, v0p, a0[j]);                                            \
      a1[j] = fma2(pr, v1p, a1[j]);                                            \
      a2[j] = fma2(pr, v2p, a2[j]);                                            \
      al[j] += pr; }

// ---------------------------------------------------------------------------
// Kernel 1: attention tiles — R11's packed dual-FP32 version, UNCHANGED
// (121.7us session best): 1152 tiles, inline prep, launch_bounds(256,5),
// float2 ext-vector inner loop (v_pk_fma_f32), pair-interleaved K/V LDS.
// ---------------------------------------------------------------------------
__global__ __launch_bounds__(256, 5) void attn_kernel(P p) {
    __shared__ float4 skv[384];      // 6 KB  pair-interleaved K/V
    __shared__ float4 sq[256];       // 4 KB  prescaled q
    __shared__ float4 spart[1024];   // 16 KB

    const int tid  = threadIdx.x;
    int tile = blockIdx.x;
    int bh   = tile / TPB;
    int r    = tile - bh * TPB;
    int s    = 0;
    while (((s + 1) * (s + 2)) / 2 <= r) ++s;
    int c    = r - (s * (s + 1)) / 2;
    int b    = bh >> 1;              // NH = 2
    int hh   = bh & 1;

    // --- inline prep: key-token K/V (pair-interleaved), query-token Q
    {
        float hK[DM];
        ln1_of(p, b, (c << 8) + tid, hK);
        float k0=0.f,k1=0.f,k2=0.f,v0=0.f,v1=0.f,v2=0.f;
        const float* wk  = p.Wk + (hh * 3) * 8;
        const float* wv_ = p.Wv + (hh * 3) * 8;
        #pragma unroll
        for (int j = 0; j < 8; ++j) {
            k0 = fmaf(wk[j],      hK[TOKD + j], k0);
            k1 = fmaf(wk[8 + j],  hK[TOKD + j], k1);
            k2 = fmaf(wk[16 + j], hK[TOKD + j], k2);
            v0 = fmaf(wv_[j],      hK[j], v0);
            v1 = fmaf(wv_[8 + j],  hK[j], v1);
            v2 = fmaf(wv_[16 + j], hK[j], v2);
        }
        float* sf = reinterpret_cast<float*>(skv);
        int o4 = ((tid >> 1) << 2) + (tid & 1);
        sf[o4]            = k0;  sf[o4 + 2]        = k1;
        sf[512 + o4]      = k2;  sf[512 + o4 + 2]  = v0;
        sf[1024 + o4]     = v1;  sf[1024 + o4 + 2] = v2;

        float hQ[DM];
        if (c != s) {
            ln1_of(p, b, (s << 8) + tid, hQ);
        } else {
            #pragma unroll
            for (int j = 0; j < DM; ++j) hQ[j] = hK[j];   // same tokens
        }
        const float QS = 1.4426950408889634f / 1.7320508075688772f; // log2e/sqrt(HD)
        float q0=0.f,q1=0.f,q2=0.f;
        const float* wq = p.Wq + (hh * 3) * 8;
        #pragma unroll
        for (int j = 0; j < 8; ++j) {
            q0 = fmaf(wq[j],      hQ[TOKD + j], q0);
            q1 = fmaf(wq[8 + j],  hQ[TOKD + j], q1);
            q2 = fmaf(wq[16 + j], hQ[TOKD + j], q2);
        }
        sq[tid] = make_float4(q0 * QS, q1 * QS, q2 * QS, 0.f);
    }
    __syncthreads();

    int wv   = tid >> 6;
    int lane = tid & 63;
    int aw   = wv << 5;              // pair-entry base (32 pairs = 64 keys)

    f2 qx2[4], qy2[4], qz2[4];
    #pragma unroll
    for (int j = 0; j < 4; ++j) {
        float4 q4 = sq[(j << 6) + lane];
        qx2[j] = (f2){q4.x, q4.x};
        qy2[j] = (f2){q4.y, q4.y};
        qz2[j] = (f2){q4.z, q4.z};
    }

    f2 a0[4], a1[4], a2[4], al[4];
    #pragma unroll
    for (int j = 0; j < 4; ++j) {
        a0[j] = (f2){0.f, 0.f}; a1[j] = (f2){0.f, 0.f};
        a2[j] = (f2){0.f, 0.f}; al[j] = (f2){0.f, 0.f};
    }

    if (c < s) {
        // fully unmasked: one A/B/C read set serves all 4 query groups
        #pragma unroll 4
        for (int i = 0; i < 32; ++i) {
            PAIR_LOAD(i)
            #pragma unroll
            for (int j = 0; j < 4; ++j) PAIR_STEP(j)
        }
    } else {
        // diagonal tile: wave wv sees keys 64wv..64wv+63.
        // group j<wv fully masked (skip); j==wv triangular; j>wv unmasked.
        #pragma unroll
        for (int j = 0; j < 4; ++j) {
            if (j < wv) continue;              // wave-uniform skip
            if (j == wv) {
                #pragma unroll 4
                for (int i = 0; i < 32; ++i) {
                    PAIR_LOAD(i)
                    PAIR_STEP_TRI(j, i)
                }
            } else {
                #pragma unroll 4
                for (int i = 0; i < 32; ++i) {
                    PAIR_LOAD(i)
                    PAIR_STEP(j)
                }
            }
        }
    }

    // merge even/odd halves; per-wave partials (16B lane stride: 2-way, free)
    #pragma unroll
    for (int j = 0; j < 4; ++j)
        spart[(wv << 8) + (j << 6) + lane] =
            make_float4(a0[j].x + a0[j].y, a1[j].x + a1[j].y,
                        a2[j].x + a2[j].y, al[j].x + al[j].y);
    __syncthreads();

    // block reduce across 4 waves; coalesced transposed pbuf store
    float4 p0 = spart[tid];
    float4 p1 = spart[256 + tid];
    float4 p2 = spart[512 + tid];
    float4 p3 = spart[768 + tid];
    float4 acc = make_float4(p0.x+p1.x+p2.x+p3.x, p0.y+p1.y+p2.y+p3.y,
                             p0.z+p1.z+p2.z+p3.z, p0.w+p1.w+p2.w+p3.w);
    p.pbuf[((size_t)bh * 8 + c) * TT + (s << 8) + tid] = acc;
}

// ---------------------------------------------------------------------------
// Kernel 2: per-token epilogue. Same math as the proven version; grid
// reshaped 128x256 -> 512x64 (one wave per block) so all 256 CUs get work
// (2 blocks/CU) instead of 128 CUs at 1 block each.
// ---------------------------------------------------------------------------
__global__ __launch_bounds__(64) void epi_kernel(P p) {
    int gid = blockIdx.x * 64 + threadIdx.x;
    if (gid >= NTOK) return;
    int t = gid & (TT - 1);
    int b = gid >> 11;
    int s = t >> 8;

    float x[DM];
    int tok = p.idx[gid];
    #pragma unroll
    for (int j = 0; j < TOKD; ++j) x[j]        = p.tok_emb[tok * TOKD + j];
    #pragma unroll
    for (int j = 0; j < POSD; ++j) x[TOKD + j] = p.pos_enc[t * POSD + j];

    float att[AD];
    #pragma unroll
    for (int hh = 0; hh < NH; ++hh) {
        const float4* pp = p.pbuf + ((size_t)(b * NH + hh) * 8) * TT + t;
        float4 acc = pp[0];
        for (int c = 1; c <= s; ++c) {
            float4 e = pp[(size_t)c * TT];
            acc.x += e.x; acc.y += e.y; acc.z += e.z; acc.w += e.w;
        }
        float inv = 1.f / acc.w;
        att[hh*3+0] = acc.x * inv;
        att[hh*3+1] = acc.y * inv;
        att[hh*3+2] = acc.z * inv;
    }

    float xo[DM];
    #pragma unroll
    for (int j = 0; j < DM; ++j) {
        float sacc = x[j];
        #pragma unroll
        for (int a = 0; a < AD; ++a) sacc = fmaf(p.Wo[j * AD + a], att[a], sacc);
        xo[j] = sacc;
    }

    float m = 0.f;
    #pragma unroll
    for (int j = 0; j < DM; ++j) m += xo[j];
    m *= (1.f / DM);
    float v = 0.f;
    #pragma unroll
    for (int j = 0; j < DM; ++j) { float d = xo[j] - m; v += d * d; }
    v *= (1.f / DM);
    float rs = rsqrtf(v + 1e-5f);
    float h2[DM];
    #pragma unroll
    for (int j = 0; j < DM; ++j)
        h2[j] = (xo[j] - m) * rs * p.ln2w[j] + p.ln2b[j];

    float g[FFND];
    #pragma unroll
    for (int cc = 0; cc < FFND; ++cc) {
        float f = p.b1[cc];
        #pragma unroll
        for (int j = 0; j < DM; ++j) f = fmaf(p.W1[cc * DM + j], h2[j], f);
        g[cc] = 0.5f * f * (1.f + erff(f * 0.70710678118654752f));
    }
    float x2[DM];
    #pragma unroll
    for (int j = 0; j < DM; ++j) {
        float sacc = xo[j] + p.b2[j];
        #pragma unroll
        for (int cc = 0; cc < FFND; ++cc) sacc = fmaf(p.W2[j * FFND + cc], g[cc], sacc);
        x2[j] = sacc;
    }

    m = 0.f;
    #pragma unroll
    for (int j = 0; j < DM; ++j) m += x2[j];
    m *= (1.f / DM);
    v = 0.f;
    #pragma unroll
    for (int j = 0; j < DM; ++j) { float d = x2[j] - m; v += d * d; }
    v *= (1.f / DM);
    rs = rsqrtf(v + 1e-5f);
    float y[DM];
    #pragma unroll
    for (int j = 0; j < DM; ++j)
        y[j] = (x2[j] - m) * rs * p.lnfw[j] + p.lnfb[j];

    float t8[TOKD];
    #pragma unroll
    for (int pp = 0; pp < TOKD; ++pp) {
        float sacc = 0.f;
        #pragma unroll
        for (int j = 0; j < DM; ++j) sacc = fmaf(p.Wh[pp * DM + j], y[j], sacc);
        t8[pp] = sacc;
    }
    float* op = p.out + (size_t)gid * VOCAB;
    #pragma unroll
    for (int vcb = 0; vcb < VOCAB; ++vcb) {
        float sacc = 0.f;
        #pragma unroll
        for (int pp = 0; pp < TOKD; ++pp)
            sacc = fmaf(t8[pp], p.tok_emb[vcb * TOKD + pp], sacc);
        op[vcb] = sacc;
    }
}

// ---------------------------------------------------------------------------
extern "C" void kernel_launch(void* const* d_in, const int* in_sizes, int n_in,
                              void* d_out, int out_size, void* d_ws, size_t ws_size,
                              hipStream_t stream) {
    P p;
    p.idx     = (const int*)d_in[0];
    p.tok_emb = (const float*)d_in[1];
    p.pos_enc = (const float*)d_in[2];
    p.Wq      = (const float*)d_in[3];
    p.Wk      = (const float*)d_in[4];
    p.Wv      = (const float*)d_in[5];
    p.Wo      = (const float*)d_in[6];
    p.ln1w    = (const float*)d_in[7];
    p.ln1b    = (const float*)d_in[8];
    p.ln2w    = (const float*)d_in[9];
    p.ln2b    = (const float*)d_in[10];
    p.lnfw    = (const float*)d_in[11];
    p.lnfb    = (const float*)d_in[12];
    p.W1      = (const float*)d_in[13];
    p.b1      = (const float*)d_in[14];
    p.W2      = (const float*)d_in[15];
    p.b2      = (const float*)d_in[16];
    p.Wh      = (const float*)d_in[17];
    p.out     = (float*)d_out;
    p.pbuf    = (float4*)d_ws;                                  // 8 MB

    attn_kernel<<<NTILE, 256, 0, stream>>>(p);
    epi_kernel<<<NTOK / 64, 64, 0, stream>>>(p);
}